// Round 7
// baseline (307.331 us; speedup 1.0000x reference)
//
#include <hip/hip_runtime.h>

typedef __bf16 bf16;
typedef __bf16 bf16x4 __attribute__((ext_vector_type(4)));
typedef __bf16 bf16x8 __attribute__((ext_vector_type(8)));
typedef float  f32x4  __attribute__((ext_vector_type(4)));

// ---------------------------------------------------------------- helpers
__device__ __forceinline__ void gld16(const void* g, void* l) {
  __builtin_amdgcn_global_load_lds(
      (const __attribute__((address_space(1))) void*)g,
      (__attribute__((address_space(3))) void*)l, 16, 0, 0);
}

// ---------------------------------------------------------------- fused fp32 -> bf16 (all three tensors, one launch)
__global__ void f2bf_all(const float* __restrict__ x, bf16* __restrict__ xo,
                         const float* __restrict__ w1, bf16* __restrict__ w1o,
                         const float* __restrict__ w2, bf16* __restrict__ w2o) {
  int i = blockIdx.x * blockDim.x + threadIdx.x;   // grid covers 2097152 float4s
  const float* in; bf16* out; int idx;
  if (i < 1048576)      { in = x;  out = xo;  idx = i; }
  else if (i < 1835008) { in = w1; out = w1o; idx = i - 1048576; }
  else                  { in = w2; out = w2o; idx = i - 1835008; }
  float4 v = reinterpret_cast<const float4*>(in)[idx];
  bf16x4 o = { (bf16)v.x, (bf16)v.y, (bf16)v.z, (bf16)v.w };
  reinterpret_cast<bf16x4*>(out)[idx] = o;
}

// ---------------------------------------------------------------- GEMM: C[M,N] = A[M,K] * B[N,K]^T + bias
// MODE 0 (BN=128): QKV epilogue. Q/K scatter to [sec][B*H][S][64] (q scaled
//   by 0.125*log2e); V section writes V^T DIRECTLY into the V-third of the
//   QKV buffer as [B*H][64][2048] (acc's 4 r-values = 4 consecutive s at
//   fixed d = one bf16x4 store) -> transpose kernel eliminated.
// MODE 1 (BN=64): out-proj epilogue -> fp32 C += bias
template<int MODE, int BN>
__global__ __launch_bounds__(256)
void gemm_bt(const bf16* __restrict__ A, const bf16* __restrict__ B,
             const float* __restrict__ bias, void* __restrict__ Cout,
             int K, int N) {
  __shared__ bf16 As[128 * 64];
  __shared__ bf16 Bs[BN * 64];
  const int tid  = threadIdx.x;
  const int wave = tid >> 6, lane = tid & 63;
  const int quad = lane >> 4, l16 = lane & 15;
  const int bm = blockIdx.x * 128, bn = blockIdx.y * BN;
  constexpr int NI  = (BN == 128) ? 4 : 2;   // 16-row groups per wave (M dir)
  constexpr int BCH = BN / 32;               // B staging chunks per wave
  const int wr = (BN == 128) ? (wave >> 1) * 64 : wave * 32;
  const int wc = (BN == 128) ? (wave & 1) * 64 : 0;
  const int arow = lane >> 3;
  const int acol = (lane & 7) * 8;

  f32x4 acc[NI][4] = {};

  const bf16* Ab = A + (size_t)bm * K;
  const bf16* Bb = B + (size_t)bn * K;

  for (int k0 = 0; k0 < K; k0 += 64) {
#pragma unroll
    for (int i = 0; i < 4; ++i) {
      int c = wave * 4 + i;
      gld16(Ab + (size_t)(c * 8 + arow) * K + k0 + acol, As + c * 512);
    }
#pragma unroll
    for (int i = 0; i < BCH; ++i) {
      int c = wave * BCH + i;
      gld16(Bb + (size_t)(c * 8 + arow) * K + k0 + acol, Bs + c * 512);
    }
    __syncthreads();
#pragma unroll
    for (int kk = 0; kk < 64; kk += 32) {
      bf16x8 af[NI], bfr[4];
#pragma unroll
      for (int i = 0; i < NI; ++i)
        af[i]  = *(const bf16x8*)(As + (wr + i * 16 + l16) * 64 + kk + quad * 8);
#pragma unroll
      for (int j = 0; j < 4; ++j)
        bfr[j] = *(const bf16x8*)(Bs + (wc + j * 16 + l16) * 64 + kk + quad * 8);
#pragma unroll
      for (int i = 0; i < NI; ++i)
#pragma unroll
        for (int j = 0; j < 4; ++j)
          acc[i][j] = __builtin_amdgcn_mfma_f32_16x16x32_bf16(af[i], bfr[j], acc[i][j], 0, 0, 0);
    }
    __syncthreads();
  }

  if constexpr (MODE == 0) {
    bf16* Q = (bf16*)Cout;  // [3][32][2048][64]; V-third holds V^T [32][64][2048]
#pragma unroll
    for (int j = 0; j < 4; ++j) {
      int col = bn + wc + j * 16 + l16;          // o in [0,3072); uniform sec per j
      float bv  = bias[col];
      int sec = col >> 10, rem = col & 1023;
      int h = rem >> 6, d = rem & 63;
      if (sec < 2) {
        float scl = (sec == 0) ? 0.125f * 1.44269504f : 1.0f;
#pragma unroll
        for (int i = 0; i < NI; ++i) {
#pragma unroll
          for (int r = 0; r < 4; ++r) {
            int row = bm + wr + i * 16 + quad * 4 + r;   // s in [0,4096)
            int b = row >> 11, si = row & 2047;
            float v = (acc[i][j][r] + bv) * scl;
            Q[(((size_t)sec * 32 + b * 16 + h) * 2048 + si) * 64 + d] = (bf16)v;
          }
        }
      } else {
        // V^T: 4 consecutive s at fixed d -> one 8B store
#pragma unroll
        for (int i = 0; i < NI; ++i) {
          int row0 = bm + wr + i * 16 + quad * 4;
          int b = row0 >> 11, si = row0 & 2047;
          bf16x4 pk = { (bf16)(acc[i][j][0] + bv), (bf16)(acc[i][j][1] + bv),
                        (bf16)(acc[i][j][2] + bv), (bf16)(acc[i][j][3] + bv) };
          *(bf16x4*)(Q + (size_t)2 * 4194304 +
                     ((size_t)(b * 16 + h) * 64 + d) * 2048 + si) = pk;
        }
      }
    }
  } else {
    float* C = (float*)Cout;
#pragma unroll
    for (int j = 0; j < 4; ++j) {
      int col = bn + wc + j * 16 + l16;
      float bv = bias[col];
#pragma unroll
      for (int i = 0; i < NI; ++i)
#pragma unroll
        for (int r = 0; r < 4; ++r) {
          int row = bm + wr + i * 16 + quad * 4 + r;
          C[(size_t)row * N + col] = acc[i][j][r] + bv;
        }
    }
  }
}

// ---------------------------------------------------------------- flash attention v6 (fixed grid)
// 512-thread blocks (8 waves), 128 q-rows/block, 16 q-rows/wave -> grid
// 16x32 = 512 blocks, 2 blocks/CU x 8 waves = 16 waves/CU (4/SIMD, 2x R4)
// while the Ks double buffer is amortized over 8 waves. S^T-form QK (lane
// holds 4 consecutive k-cols) -> P transpose = 8 ds_write_b64/tile; K
// double-buffered in LDS (pad 72, one barrier/tile); Q frags in regs; V
// frags direct from global V^T (L1/L2-served). Row sums per-lane + 2 end
// shuffles. Q pre-scaled by 0.125*log2e -> bare exp2.
__global__ __launch_bounds__(512, 4)
void attn_kernel(const bf16* __restrict__ QKV, const bf16* __restrict__ Vt,
                 bf16* __restrict__ O) {
  __shared__ bf16 Ks[2][128 * 72];     // 36864 B
  __shared__ bf16 Ps[8][16 * 136];     // 34816 B -> total 71680 B (2 blk/CU)

  const int bh = blockIdx.y;
  const int q0 = blockIdx.x * 128;
  const bf16* Qg = QKV + ((size_t)bh * 2048 + q0) * 64;
  const bf16* Kg = QKV + (size_t)32 * 2048 * 64 + (size_t)bh * 2048 * 64;
  const bf16* Vg = Vt + (size_t)bh * 64 * 2048;

  const int tid  = threadIdx.x;
  const int wave = tid >> 6, lane = tid & 63;
  const int quad = lane >> 4, l16 = lane & 15;
  const int srow = tid >> 3;            // 0..63 staging row
  const int scol = (tid & 7) * 8;       // 0..56 staging col
  bf16* Pw = &Ps[wave][0];

  // Q fragments in registers (B-operand), reused across all 16 K-tiles
  bf16x8 aq[2];
#pragma unroll
  for (int kh = 0; kh < 2; ++kh)
    aq[kh] = *(const bf16x8*)(Qg + (size_t)(wave * 16 + l16) * 64 + kh * 32 + quad * 8);

  // preload K tile 0 into Ks[0] (cooperative across 512 threads)
  {
    bf16x8 kreg[2];
#pragma unroll
    for (int ch = 0; ch < 2; ++ch)
      kreg[ch] = *(const bf16x8*)(Kg + (size_t)(ch * 64 + srow) * 64 + scol);
#pragma unroll
    for (int ch = 0; ch < 2; ++ch)
      *(bf16x8*)(&Ks[0][(ch * 64 + srow) * 72 + scol]) = kreg[ch];
  }
  __syncthreads();

  float rs = 0.f;                       // per-lane partial row sum (qrow = l16)
  f32x4 o[4] = {};

  for (int kt = 0; kt < 16; ++kt) {
    const int cur = kt & 1;

    // prefetch next K tile to regs (independent of LDS)
    bf16x8 kreg[2];
    if (kt < 15) {
#pragma unroll
      for (int ch = 0; ch < 2; ++ch)
        kreg[ch] = *(const bf16x8*)(Kg + (size_t)((kt + 1) * 128 + ch * 64 + srow) * 64 + scol);
    }
    // prefetch V fragments for this tile (consumed after QK+exp)
    bf16x8 bv[4][4];
#pragma unroll
    for (int kk = 0; kk < 4; ++kk)
#pragma unroll
      for (int oj = 0; oj < 4; ++oj)
        bv[kk][oj] = *(const bf16x8*)(Vg + (size_t)(oj * 16 + l16) * 2048 +
                                      kt * 128 + kk * 32 + quad * 8);

    // ---- S^T = K Q^T : lane holds S[qrow=l16][kcol=ni*16+quad*4+r]
    f32x4 s[8] = {};
#pragma unroll
    for (int kh = 0; kh < 2; ++kh) {
#pragma unroll
      for (int ni = 0; ni < 8; ++ni) {
        bf16x8 bk = *(const bf16x8*)(&Ks[cur][(ni * 16 + l16) * 72 + kh * 32 + quad * 8]);
        s[ni] = __builtin_amdgcn_mfma_f32_16x16x32_bf16(bk, aq[kh], s[ni], 0, 0, 0);
      }
    }

    // write next K tile into the other LDS buffer
    if (kt < 15) {
#pragma unroll
      for (int ch = 0; ch < 2; ++ch)
        *(bf16x8*)(&Ks[cur ^ 1][(ch * 64 + srow) * 72 + scol]) = kreg[ch];
    }

    // ---- P = exp2(S): 4 consecutive kcols/lane -> one b64 LDS write each
#pragma unroll
    for (int ni = 0; ni < 8; ++ni) {
      float p0 = __builtin_amdgcn_exp2f(s[ni][0]);
      float p1 = __builtin_amdgcn_exp2f(s[ni][1]);
      float p2 = __builtin_amdgcn_exp2f(s[ni][2]);
      float p3 = __builtin_amdgcn_exp2f(s[ni][3]);
      rs += (p0 + p1) + (p2 + p3);
      bf16x4 pk = { (bf16)p0, (bf16)p1, (bf16)p2, (bf16)p3 };
      *(bf16x4*)(Pw + l16 * 136 + ni * 16 + quad * 4) = pk;
    }

    // ---- O += P V  (per-wave Ps; lgkmcnt orders write->read, no barrier)
#pragma unroll
    for (int kk = 0; kk < 4; ++kk) {
      bf16x8 ap = *(const bf16x8*)(Pw + l16 * 136 + kk * 32 + quad * 8);
#pragma unroll
      for (int oj = 0; oj < 4; ++oj)
        o[oj] = __builtin_amdgcn_mfma_f32_16x16x32_bf16(ap, bv[kk][oj], o[oj], 0, 0, 0);
    }

    __syncthreads();   // all waves done writing Ks[cur^1] / reading Ks[cur]
  }

  // ---- finalize row sums: quads hold partials for row l16
  rs += __shfl_xor(rs, 16);
  rs += __shfl_xor(rs, 32);

  // ---- epilogue: redistribute 1/l to C-layout rows, write bf16
  const int b = bh >> 4, h = bh & 15;
#pragma unroll
  for (int r = 0; r < 4; ++r) {
    float lsum = __shfl(rs, quad * 4 + r);   // sum for row quad*4+r (at lane l16=row)
    float inv = 1.0f / lsum;
    int row = q0 + wave * 16 + quad * 4 + r;
#pragma unroll
    for (int oj = 0; oj < 4; ++oj)
      O[((size_t)(b * 2048 + row)) * 1024 + h * 64 + oj * 16 + l16] =
          (bf16)(o[oj][r] * inv);
  }
}

// ---------------------------------------------------------------- launch
extern "C" void kernel_launch(void* const* d_in, const int* in_sizes, int n_in,
                              void* d_out, int out_size, void* d_ws, size_t ws_size,
                              hipStream_t stream) {
  const float* x      = (const float*)d_in[0];   // [2,2048,1024]
  const float* qkv_w  = (const float*)d_in[1];   // [3072,1024]
  const float* qkv_b  = (const float*)d_in[2];   // [3072]
  const float* out_w  = (const float*)d_in[3];   // [1024,1024]
  const float* out_b  = (const float*)d_in[4];   // [1024]
  float* out = (float*)d_out;                    // [2,2048,1024] fp32

  char* ws = (char*)d_ws;
  bf16* Xb   = (bf16*)(ws);                      // 8 MB
  bf16* Wqkv = (bf16*)(ws + 8388608);            // 6 MB
  bf16* Wout = (bf16*)(ws + 14680064);           // 2 MB
  bf16* QKV  = (bf16*)(ws + 16777216);           // 24 MB: [Q][K] + V^T in third section
  bf16* At   = (bf16*)(ws + 41943040);           // 8 MB attn output [B,S,1024]
  bf16* VtP  = QKV + (size_t)2 * 32 * 2048 * 64; // V^T [32][64][2048] (written by gemm1)

  f2bf_all<<<8192, 256, 0, stream>>>(x, Xb, qkv_w, Wqkv, out_w, Wout);

  gemm_bt<0, 128><<<dim3(32, 24), 256, 0, stream>>>(Xb, Wqkv, qkv_b, (void*)QKV, 1024, 3072);

  // 2048 q-rows / 128 per block = 16 x-blocks (R6 bug: was 4)
  attn_kernel<<<dim3(16, 32), 512, 0, stream>>>(QKV, VtP, At);

  gemm_bt<1, 64><<<dim3(32, 16), 256, 0, stream>>>(At, Wout, out_b, (void*)out, 1024, 1024);
}

// Round 8
// 278.868 us; speedup vs baseline: 1.1021x; 1.1021x over previous
//
#include <hip/hip_runtime.h>
#include <string.h>

typedef __bf16 bf16;
typedef __bf16 bf16x4 __attribute__((ext_vector_type(4)));
typedef __bf16 bf16x8 __attribute__((ext_vector_type(8)));
typedef float  f32x4  __attribute__((ext_vector_type(4)));
typedef float  f32x16 __attribute__((ext_vector_type(16)));
typedef short  s16x4  __attribute__((ext_vector_type(4)));

// ---------------------------------------------------------------- helpers
__device__ __forceinline__ void gld16(const void* g, void* l) {
  __builtin_amdgcn_global_load_lds(
      (const __attribute__((address_space(1))) void*)g,
      (__attribute__((address_space(3))) void*)l, 16, 0, 0);
}
__device__ __forceinline__ s16x4 b2s(bf16x4 v) {
  s16x4 r; __builtin_memcpy(&r, &v, 8); return r;
}

// ---------------------------------------------------------------- fused fp32 -> bf16 (all three tensors, one launch)
__global__ void f2bf_all(const float* __restrict__ x, bf16* __restrict__ xo,
                         const float* __restrict__ w1, bf16* __restrict__ w1o,
                         const float* __restrict__ w2, bf16* __restrict__ w2o) {
  int i = blockIdx.x * blockDim.x + threadIdx.x;   // grid covers 2097152 float4s
  const float* in; bf16* out; int idx;
  if (i < 1048576)      { in = x;  out = xo;  idx = i; }
  else if (i < 1835008) { in = w1; out = w1o; idx = i - 1048576; }
  else                  { in = w2; out = w2o; idx = i - 1835008; }
  float4 v = reinterpret_cast<const float4*>(in)[idx];
  bf16x4 o = { (bf16)v.x, (bf16)v.y, (bf16)v.z, (bf16)v.w };
  reinterpret_cast<bf16x4*>(out)[idx] = o;
}

// ---------------------------------------------------------------- GEMM: C[M,N] = A[M,K] * B[N,K]^T + bias
// MODE 0 (BN=128): QKV epilogue. Q/K scatter to [sec][B*H][S][64] (q scaled
//   by 0.125*log2e); V section writes V^T into the V-third of QKV as
//   [B*H][64][2048] (4 consecutive s at fixed d = one bf16x4 store).
// MODE 1 (BN=64): out-proj epilogue -> fp32 C += bias
template<int MODE, int BN>
__global__ __launch_bounds__(256)
void gemm_bt(const bf16* __restrict__ A, const bf16* __restrict__ B,
             const float* __restrict__ bias, void* __restrict__ Cout,
             int K, int N) {
  __shared__ bf16 As[128 * 64];
  __shared__ bf16 Bs[BN * 64];
  const int tid  = threadIdx.x;
  const int wave = tid >> 6, lane = tid & 63;
  const int quad = lane >> 4, l16 = lane & 15;
  const int bm = blockIdx.x * 128, bn = blockIdx.y * BN;
  constexpr int NI  = (BN == 128) ? 4 : 2;
  constexpr int BCH = BN / 32;
  const int wr = (BN == 128) ? (wave >> 1) * 64 : wave * 32;
  const int wc = (BN == 128) ? (wave & 1) * 64 : 0;
  const int arow = lane >> 3;
  const int acol = (lane & 7) * 8;

  f32x4 acc[NI][4] = {};

  const bf16* Ab = A + (size_t)bm * K;
  const bf16* Bb = B + (size_t)bn * K;

  for (int k0 = 0; k0 < K; k0 += 64) {
#pragma unroll
    for (int i = 0; i < 4; ++i) {
      int c = wave * 4 + i;
      gld16(Ab + (size_t)(c * 8 + arow) * K + k0 + acol, As + c * 512);
    }
#pragma unroll
    for (int i = 0; i < BCH; ++i) {
      int c = wave * BCH + i;
      gld16(Bb + (size_t)(c * 8 + arow) * K + k0 + acol, Bs + c * 512);
    }
    __syncthreads();
#pragma unroll
    for (int kk = 0; kk < 64; kk += 32) {
      bf16x8 af[NI], bfr[4];
#pragma unroll
      for (int i = 0; i < NI; ++i)
        af[i]  = *(const bf16x8*)(As + (wr + i * 16 + l16) * 64 + kk + quad * 8);
#pragma unroll
      for (int j = 0; j < 4; ++j)
        bfr[j] = *(const bf16x8*)(Bs + (wc + j * 16 + l16) * 64 + kk + quad * 8);
#pragma unroll
      for (int i = 0; i < NI; ++i)
#pragma unroll
        for (int j = 0; j < 4; ++j)
          acc[i][j] = __builtin_amdgcn_mfma_f32_16x16x32_bf16(af[i], bfr[j], acc[i][j], 0, 0, 0);
    }
    __syncthreads();
  }

  if constexpr (MODE == 0) {
    bf16* Q = (bf16*)Cout;  // [3][32][2048][64]; V-third holds V^T [32][64][2048]
#pragma unroll
    for (int j = 0; j < 4; ++j) {
      int col = bn + wc + j * 16 + l16;
      float bv  = bias[col];
      int sec = col >> 10, rem = col & 1023;
      int h = rem >> 6, d = rem & 63;
      if (sec < 2) {
        float scl = (sec == 0) ? 0.125f * 1.44269504f : 1.0f;
#pragma unroll
        for (int i = 0; i < NI; ++i) {
#pragma unroll
          for (int r = 0; r < 4; ++r) {
            int row = bm + wr + i * 16 + quad * 4 + r;
            int b = row >> 11, si = row & 2047;
            float v = (acc[i][j][r] + bv) * scl;
            Q[(((size_t)sec * 32 + b * 16 + h) * 2048 + si) * 64 + d] = (bf16)v;
          }
        }
      } else {
#pragma unroll
        for (int i = 0; i < NI; ++i) {
          int row0 = bm + wr + i * 16 + quad * 4;
          int b = row0 >> 11, si = row0 & 2047;
          bf16x4 pk = { (bf16)(acc[i][j][0] + bv), (bf16)(acc[i][j][1] + bv),
                        (bf16)(acc[i][j][2] + bv), (bf16)(acc[i][j][3] + bv) };
          *(bf16x4*)(Q + (size_t)2 * 4194304 +
                     ((size_t)(b * 16 + h) * 64 + d) * 2048 + si) = pk;
        }
      }
    }
  } else {
    float* C = (float*)Cout;
#pragma unroll
    for (int j = 0; j < 4; ++j) {
      int col = bn + wc + j * 16 + l16;
      float bv = bias[col];
#pragma unroll
      for (int i = 0; i < NI; ++i)
#pragma unroll
        for (int r = 0; r < 4; ++r) {
          int row = bm + wr + i * 16 + quad * 4 + r;
          C[(size_t)row * N + col] = acc[i][j][r] + bv;
        }
    }
  }
}

// ---------------------------------------------------------------- flash attention v7
// 32x32-shape pipeline, P NEVER touches LDS:
//   S^T = K.Q^T via mfma_f32_32x32x16_bf16 (A=K-rows from LDS, B=Q regs).
//   C-layout: col=lane&31=q, row k' = (reg&3)+8(reg>>2)+4(lane>>5).
//   For PV via mfma_f32_32x32x8bf16_1k, the A-operand (P, m=q, k-window of 8:
//   k = 8c+4h+j) is EXACTLY C-regs {4c..4c+3} in-lane -> P stays in VGPRs.
//   V^T b64 B-frags direct from global (k agreement: 4h+j within window).
// 256 threads, 32 q-rows/wave, 128 q-rows/block, grid 16x32. K-tile double
// buffered in LDS (pad 72, regs->LDS, one barrier/tile). Row sums per-lane
// + one shfl_xor(32); epilogue redistributes 1/l with 16 shfls.
__global__ __launch_bounds__(256, 2)
void attn_kernel(const bf16* __restrict__ QKV, const bf16* __restrict__ Vt,
                 bf16* __restrict__ O) {
  __shared__ bf16 Ks[2][128 * 72];     // 36864 B total LDS

  const int bh = blockIdx.y;
  const int q0 = blockIdx.x * 128;
  const bf16* Qg = QKV + ((size_t)bh * 2048 + q0) * 64;
  const bf16* Kg = QKV + (size_t)32 * 2048 * 64 + (size_t)bh * 2048 * 64;
  const bf16* Vg = Vt + (size_t)bh * 64 * 2048;

  const int tid  = threadIdx.x;
  const int wave = tid >> 6, lane = tid & 63;
  const int l31 = lane & 31, hh = lane >> 5;
  const int srow = tid >> 3;            // 0..31 staging row
  const int scol = (tid & 7) * 8;       // 0..56 staging col

  // Q B-fragments: B[n=q=l31][k = dc*16 + hh*8 + j], reused all 16 K-tiles
  bf16x8 bq[4];
#pragma unroll
  for (int dc = 0; dc < 4; ++dc)
    bq[dc] = *(const bf16x8*)(Qg + (size_t)(wave * 32 + l31) * 64 + dc * 16 + hh * 8);

  // preload K tile 0 into Ks[0]
  {
    bf16x8 k0[4];
#pragma unroll
    for (int ch = 0; ch < 4; ++ch)
      k0[ch] = *(const bf16x8*)(Kg + (size_t)(ch * 32 + srow) * 64 + scol);
#pragma unroll
    for (int ch = 0; ch < 4; ++ch)
      *(bf16x8*)(&Ks[0][(ch * 32 + srow) * 72 + scol]) = k0[ch];
  }
  __syncthreads();

  f32x16 o0 = {}, o1 = {};              // O[q-rows][d=l31] , d+32
  float rs = 0.f;                       // per-lane partial row sum for q=l31
  bf16x4 vv[2][4][2];                   // V frags, ping-pong per sb

  for (int kt = 0; kt < 16; ++kt) {
    const int cur = kt & 1;

    // prefetch next K tile to regs
    bf16x8 kreg[4];
    if (kt < 15) {
#pragma unroll
      for (int ch = 0; ch < 4; ++ch)
        kreg[ch] = *(const bf16x8*)(Kg + (size_t)((kt + 1) * 128 + ch * 32 + srow) * 64 + scol);
    }
    // V frags for sb=0: Vt[dt*32+l31][kt*128 + c*8 + hh*4 + j]
#pragma unroll
    for (int c = 0; c < 4; ++c)
#pragma unroll
      for (int dt = 0; dt < 2; ++dt)
        vv[0][c][dt] = *(const bf16x4*)(Vg + (size_t)(dt * 32 + l31) * 2048 +
                                        kt * 128 + c * 8 + hh * 4);

#pragma unroll
    for (int sb = 0; sb < 4; ++sb) {
      // ---- S^T block: 32 k-rows x 32 q, accumulate over d
      f32x16 s = {};
#pragma unroll
      for (int dc = 0; dc < 4; ++dc) {
        bf16x8 ak = *(const bf16x8*)(&Ks[cur][(sb * 32 + l31) * 72 + dc * 16 + hh * 8]);
        s = __builtin_amdgcn_mfma_f32_32x32x16_bf16(ak, bq[dc], s, 0, 0, 0);
      }

      if (sb == 0 && kt < 15) {
#pragma unroll
        for (int ch = 0; ch < 4; ++ch)
          *(bf16x8*)(&Ks[cur ^ 1][(ch * 32 + srow) * 72 + scol]) = kreg[ch];
      }
      if (sb < 3) {
#pragma unroll
        for (int c = 0; c < 4; ++c)
#pragma unroll
          for (int dt = 0; dt < 2; ++dt)
            vv[(sb + 1) & 1][c][dt] =
                *(const bf16x4*)(Vg + (size_t)(dt * 32 + l31) * 2048 +
                                 kt * 128 + (sb + 1) * 32 + c * 8 + hh * 4);
      }

      // ---- P = exp2(S), pack in-lane into PV A-frags
      bf16x4 pk[4];
#pragma unroll
      for (int g = 0; g < 4; ++g) {
        float p0 = __builtin_amdgcn_exp2f(s[4 * g + 0]);
        float p1 = __builtin_amdgcn_exp2f(s[4 * g + 1]);
        float p2 = __builtin_amdgcn_exp2f(s[4 * g + 2]);
        float p3 = __builtin_amdgcn_exp2f(s[4 * g + 3]);
        rs += (p0 + p1) + (p2 + p3);
        bf16x4 t = { (bf16)p0, (bf16)p1, (bf16)p2, (bf16)p3 };
        pk[g] = t;
      }

      // ---- O += P V : A=P (m=q, regs 4c..4c+3), B=V^T (n=d)
#pragma unroll
      for (int c = 0; c < 4; ++c) {
        o0 = __builtin_amdgcn_mfma_f32_32x32x8bf16_1k(b2s(pk[c]), b2s(vv[sb & 1][c][0]), o0, 0, 0, 0);
        o1 = __builtin_amdgcn_mfma_f32_32x32x8bf16_1k(b2s(pk[c]), b2s(vv[sb & 1][c][1]), o1, 0, 0, 0);
      }
    }
    __syncthreads();   // Ks[cur^1] writes done; Ks[cur] reads done
  }

  // ---- finalize row sums (halves hh=0/1 hold disjoint k for q=l31)
  rs += __shfl_xor(rs, 32);
  float inv = 1.0f / rs;

  // ---- epilogue: O rows q' = 8g+4hh+j, cols d = dt*32+l31
  const int b = bh >> 4, head = bh & 15;
#pragma unroll
  for (int g = 0; g < 4; ++g)
#pragma unroll
    for (int j = 0; j < 4; ++j) {
      float iv = __shfl(inv, 8 * g + 4 * hh + j);   // inv lives at lane l31=q'
      int row = q0 + wave * 32 + 8 * g + 4 * hh + j;
      size_t base = ((size_t)(b * 2048 + row)) * 1024 + head * 64;
      O[base + l31]      = (bf16)(o0[4 * g + j] * iv);
      O[base + 32 + l31] = (bf16)(o1[4 * g + j] * iv);
    }
}

// ---------------------------------------------------------------- launch
extern "C" void kernel_launch(void* const* d_in, const int* in_sizes, int n_in,
                              void* d_out, int out_size, void* d_ws, size_t ws_size,
                              hipStream_t stream) {
  const float* x      = (const float*)d_in[0];   // [2,2048,1024]
  const float* qkv_w  = (const float*)d_in[1];   // [3072,1024]
  const float* qkv_b  = (const float*)d_in[2];   // [3072]
  const float* out_w  = (const float*)d_in[3];   // [1024,1024]
  const float* out_b  = (const float*)d_in[4];   // [1024]
  float* out = (float*)d_out;                    // [2,2048,1024] fp32

  char* ws = (char*)d_ws;
  bf16* Xb   = (bf16*)(ws);                      // 8 MB
  bf16* Wqkv = (bf16*)(ws + 8388608);            // 6 MB
  bf16* Wout = (bf16*)(ws + 14680064);           // 2 MB
  bf16* QKV  = (bf16*)(ws + 16777216);           // 24 MB: [Q][K] + V^T third
  bf16* At   = (bf16*)(ws + 41943040);           // 8 MB attn output [B,S,1024]
  bf16* VtP  = QKV + (size_t)2 * 32 * 2048 * 64; // V^T [32][64][2048]

  f2bf_all<<<8192, 256, 0, stream>>>(x, Xb, qkv_w, Wqkv, out_w, Wout);

  gemm_bt<0, 128><<<dim3(32, 24), 256, 0, stream>>>(Xb, Wqkv, qkv_b, (void*)QKV, 1024, 3072);

  attn_kernel<<<dim3(16, 32), 256, 0, stream>>>(QKV, VtP, At);

  gemm_bt<1, 64><<<dim3(32, 16), 256, 0, stream>>>(At, Wout, out_b, (void*)out, 1024, 1024);
}

// Round 9
// 224.303 us; speedup vs baseline: 1.3702x; 1.2433x over previous
//
#include <hip/hip_runtime.h>

typedef __bf16 bf16;
typedef __bf16 bf16x4 __attribute__((ext_vector_type(4)));
typedef __bf16 bf16x8 __attribute__((ext_vector_type(8)));
typedef float  f32x4  __attribute__((ext_vector_type(4)));

// ---------------------------------------------------------------- helpers
__device__ __forceinline__ void gld16(const void* g, void* l) {
  __builtin_amdgcn_global_load_lds(
      (const __attribute__((address_space(1))) void*)g,
      (__attribute__((address_space(3))) void*)l, 16, 0, 0);
}

// ---------------------------------------------------------------- fused fp32 -> bf16 (all three tensors, one launch)
__global__ void f2bf_all(const float* __restrict__ x, bf16* __restrict__ xo,
                         const float* __restrict__ w1, bf16* __restrict__ w1o,
                         const float* __restrict__ w2, bf16* __restrict__ w2o) {
  int i = blockIdx.x * blockDim.x + threadIdx.x;   // grid covers 2097152 float4s
  const float* in; bf16* out; int idx;
  if (i < 1048576)      { in = x;  out = xo;  idx = i; }
  else if (i < 1835008) { in = w1; out = w1o; idx = i - 1048576; }
  else                  { in = w2; out = w2o; idx = i - 1835008; }
  float4 v = reinterpret_cast<const float4*>(in)[idx];
  bf16x4 o = { (bf16)v.x, (bf16)v.y, (bf16)v.z, (bf16)v.w };
  reinterpret_cast<bf16x4*>(out)[idx] = o;
}

// ---------------------------------------------------------------- GEMM: C[M,N] = A[M,K] * B[N,K]^T + bias
// MODE 0 (BN=128): QKV epilogue. Q/K scatter to [sec][B*H][S][64] (q scaled
//   by 0.125*log2e); V section writes V^T into the V-third of QKV as
//   [B*H][64][2048] (4 consecutive s at fixed d = one bf16x4 store).
// MODE 1 (BN=64): out-proj epilogue -> fp32 C += bias
template<int MODE, int BN>
__global__ __launch_bounds__(256)
void gemm_bt(const bf16* __restrict__ A, const bf16* __restrict__ B,
             const float* __restrict__ bias, void* __restrict__ Cout,
             int K, int N) {
  __shared__ bf16 As[128 * 64];
  __shared__ bf16 Bs[BN * 64];
  const int tid  = threadIdx.x;
  const int wave = tid >> 6, lane = tid & 63;
  const int quad = lane >> 4, l16 = lane & 15;
  const int bm = blockIdx.x * 128, bn = blockIdx.y * BN;
  constexpr int NI  = (BN == 128) ? 4 : 2;
  constexpr int BCH = BN / 32;
  const int wr = (BN == 128) ? (wave >> 1) * 64 : wave * 32;
  const int wc = (BN == 128) ? (wave & 1) * 64 : 0;
  const int arow = lane >> 3;
  const int acol = (lane & 7) * 8;

  f32x4 acc[NI][4] = {};

  const bf16* Ab = A + (size_t)bm * K;
  const bf16* Bb = B + (size_t)bn * K;

  for (int k0 = 0; k0 < K; k0 += 64) {
#pragma unroll
    for (int i = 0; i < 4; ++i) {
      int c = wave * 4 + i;
      gld16(Ab + (size_t)(c * 8 + arow) * K + k0 + acol, As + c * 512);
    }
#pragma unroll
    for (int i = 0; i < BCH; ++i) {
      int c = wave * BCH + i;
      gld16(Bb + (size_t)(c * 8 + arow) * K + k0 + acol, Bs + c * 512);
    }
    __syncthreads();
#pragma unroll
    for (int kk = 0; kk < 64; kk += 32) {
      bf16x8 af[NI], bfr[4];
#pragma unroll
      for (int i = 0; i < NI; ++i)
        af[i]  = *(const bf16x8*)(As + (wr + i * 16 + l16) * 64 + kk + quad * 8);
#pragma unroll
      for (int j = 0; j < 4; ++j)
        bfr[j] = *(const bf16x8*)(Bs + (wc + j * 16 + l16) * 64 + kk + quad * 8);
#pragma unroll
      for (int i = 0; i < NI; ++i)
#pragma unroll
        for (int j = 0; j < 4; ++j)
          acc[i][j] = __builtin_amdgcn_mfma_f32_16x16x32_bf16(af[i], bfr[j], acc[i][j], 0, 0, 0);
    }
    __syncthreads();
  }

  if constexpr (MODE == 0) {
    bf16* Q = (bf16*)Cout;  // [3][32][2048][64]; V-third holds V^T [32][64][2048]
#pragma unroll
    for (int j = 0; j < 4; ++j) {
      int col = bn + wc + j * 16 + l16;
      float bv  = bias[col];
      int sec = col >> 10, rem = col & 1023;
      int h = rem >> 6, d = rem & 63;
      if (sec < 2) {
        float scl = (sec == 0) ? 0.125f * 1.44269504f : 1.0f;
#pragma unroll
        for (int i = 0; i < NI; ++i) {
#pragma unroll
          for (int r = 0; r < 4; ++r) {
            int row = bm + wr + i * 16 + quad * 4 + r;
            int b = row >> 11, si = row & 2047;
            float v = (acc[i][j][r] + bv) * scl;
            Q[(((size_t)sec * 32 + b * 16 + h) * 2048 + si) * 64 + d] = (bf16)v;
          }
        }
      } else {
#pragma unroll
        for (int i = 0; i < NI; ++i) {
          int row0 = bm + wr + i * 16 + quad * 4;
          int b = row0 >> 11, si = row0 & 2047;
          bf16x4 pk = { (bf16)(acc[i][j][0] + bv), (bf16)(acc[i][j][1] + bv),
                        (bf16)(acc[i][j][2] + bv), (bf16)(acc[i][j][3] + bv) };
          *(bf16x4*)(Q + (size_t)2 * 4194304 +
                     ((size_t)(b * 16 + h) * 64 + d) * 2048 + si) = pk;
        }
      }
    }
  } else {
    float* C = (float*)Cout;
#pragma unroll
    for (int j = 0; j < 4; ++j) {
      int col = bn + wc + j * 16 + l16;
      float bv = bias[col];
#pragma unroll
      for (int i = 0; i < NI; ++i)
#pragma unroll
        for (int r = 0; r < 4; ++r) {
          int row = bm + wr + i * 16 + quad * 4 + r;
          C[(size_t)row * N + col] = acc[i][j][r] + bv;
        }
    }
  }
}

// ---------------------------------------------------------------- flash attention v8 = R4 structure + XCD-local grid
// Grid (bh=32, q_tile=16): linear block id = bh + 32*q_tile, so blk%8 =
// bh%8 -> all 16 q-tiles of a head land on ONE XCD (m09: blk->XCD = blk%8).
// Per-XCD K+V working set = 4 heads x 1MB = 4MB = L2; the 16 co-resident
// q-tiles hit each K/V tile in L2 instead of refetching from HBM (R4
// measured 3x overfetch: 69.7MB vs 24MB footprint, q-major grid).
// Structure (R4, proven 77.9us): 256 thr, 32 q-rows/wave, 128 q-rows/block,
// S^T-form QK (lane holds 4 consecutive k-cols -> P transpose = b64 writes,
// row sums = per-lane adds), K dbuf in LDS (pad 72, 1 barrier/tile), Q frags
// in regs, V frags direct from global V^T. Q pre-scaled 0.125*log2e -> exp2.
__global__ __launch_bounds__(256, 2)
void attn_kernel(const bf16* __restrict__ QKV, const bf16* __restrict__ Vt,
                 bf16* __restrict__ O) {
  __shared__ bf16 Ks[2][128 * 72];
  __shared__ bf16 Ps[4][32 * 136];

  const int bh = blockIdx.x;               // XCD-locality: bh is the fast dim
  const int q0 = blockIdx.y * 128;
  const bf16* Qg = QKV + ((size_t)bh * 2048 + q0) * 64;
  const bf16* Kg = QKV + (size_t)32 * 2048 * 64 + (size_t)bh * 2048 * 64;
  const bf16* Vg = Vt + (size_t)bh * 64 * 2048;

  const int tid  = threadIdx.x;
  const int wave = tid >> 6, lane = tid & 63;
  const int quad = lane >> 4, l16 = lane & 15;
  const int srow = tid >> 3;            // 0..31 staging row
  const int scol = (tid & 7) * 8;       // 0..56 staging col
  bf16* Pw = &Ps[wave][0];

  // Q fragments in registers (B-operand), reused across all 16 K-tiles
  bf16x8 aq[2][2];
#pragma unroll
  for (int i = 0; i < 2; ++i)
#pragma unroll
    for (int kh = 0; kh < 2; ++kh)
      aq[i][kh] = *(const bf16x8*)(Qg + (size_t)(wave * 32 + i * 16 + l16) * 64 +
                                   kh * 32 + quad * 8);

  // preload K tile 0 into Ks[0]
  {
    bf16x8 kreg[4];
#pragma unroll
    for (int ch = 0; ch < 4; ++ch)
      kreg[ch] = *(const bf16x8*)(Kg + (size_t)(ch * 32 + srow) * 64 + scol);
#pragma unroll
    for (int ch = 0; ch < 4; ++ch)
      *(bf16x8*)(&Ks[0][(ch * 32 + srow) * 72 + scol]) = kreg[ch];
  }
  __syncthreads();

  float rs[2] = {0.f, 0.f};             // per-lane partial row sums (qrow = i*16+l16)
  f32x4 o[2][4] = {};

  for (int kt = 0; kt < 16; ++kt) {
    const int cur = kt & 1;

    // prefetch next K tile to regs (independent of LDS)
    bf16x8 kreg[4];
    if (kt < 15) {
#pragma unroll
      for (int ch = 0; ch < 4; ++ch)
        kreg[ch] = *(const bf16x8*)(Kg + (size_t)((kt + 1) * 128 + ch * 32 + srow) * 64 + scol);
    }
    // prefetch V fragments for this tile
    bf16x8 bv[4][4];
#pragma unroll
    for (int kk = 0; kk < 4; ++kk)
#pragma unroll
      for (int oj = 0; oj < 4; ++oj)
        bv[kk][oj] = *(const bf16x8*)(Vg + (size_t)(oj * 16 + l16) * 2048 +
                                      kt * 128 + kk * 32 + quad * 8);

    // ---- S^T = K Q^T : lane holds S[qrow=l16][kcol=ni*16+quad*4+r]
    f32x4 s[2][8] = {};
#pragma unroll
    for (int kh = 0; kh < 2; ++kh) {
#pragma unroll
      for (int ni = 0; ni < 8; ++ni) {
        bf16x8 bk = *(const bf16x8*)(&Ks[cur][(ni * 16 + l16) * 72 + kh * 32 + quad * 8]);
        s[0][ni] = __builtin_amdgcn_mfma_f32_16x16x32_bf16(bk, aq[0][kh], s[0][ni], 0, 0, 0);
        s[1][ni] = __builtin_amdgcn_mfma_f32_16x16x32_bf16(bk, aq[1][kh], s[1][ni], 0, 0, 0);
      }
    }

    // write next K tile into the other LDS buffer
    if (kt < 15) {
#pragma unroll
      for (int ch = 0; ch < 4; ++ch)
        *(bf16x8*)(&Ks[cur ^ 1][(ch * 32 + srow) * 72 + scol]) = kreg[ch];
    }

    // ---- P = exp2(S): 4 consecutive kcols/lane -> one b64 LDS write each
#pragma unroll
    for (int i = 0; i < 2; ++i)
#pragma unroll
      for (int ni = 0; ni < 8; ++ni) {
        float p0 = __builtin_amdgcn_exp2f(s[i][ni][0]);
        float p1 = __builtin_amdgcn_exp2f(s[i][ni][1]);
        float p2 = __builtin_amdgcn_exp2f(s[i][ni][2]);
        float p3 = __builtin_amdgcn_exp2f(s[i][ni][3]);
        rs[i] += (p0 + p1) + (p2 + p3);
        bf16x4 pk = { (bf16)p0, (bf16)p1, (bf16)p2, (bf16)p3 };
        *(bf16x4*)(Pw + (i * 16 + l16) * 136 + ni * 16 + quad * 4) = pk;
      }

    // ---- O += P V  (per-wave Ps; lgkmcnt orders write->read, no barrier)
#pragma unroll
    for (int kk = 0; kk < 4; ++kk) {
#pragma unroll
      for (int i = 0; i < 2; ++i) {
        bf16x8 ap = *(const bf16x8*)(Pw + (i * 16 + l16) * 136 + kk * 32 + quad * 8);
#pragma unroll
        for (int oj = 0; oj < 4; ++oj)
          o[i][oj] = __builtin_amdgcn_mfma_f32_16x16x32_bf16(ap, bv[kk][oj], o[i][oj], 0, 0, 0);
      }
    }

    __syncthreads();   // all waves done writing Ks[cur^1] / reading Ks[cur]
  }

  // ---- finalize row sums: quads hold partials for row l16
#pragma unroll
  for (int i = 0; i < 2; ++i) {
    rs[i] += __shfl_xor(rs[i], 16);
    rs[i] += __shfl_xor(rs[i], 32);
  }

  // ---- epilogue: redistribute 1/l to C-layout rows, write bf16
  const int b = bh >> 4, h = bh & 15;
#pragma unroll
  for (int i = 0; i < 2; ++i)
#pragma unroll
    for (int r = 0; r < 4; ++r) {
      float lsum = __shfl(rs[i], quad * 4 + r);   // sum for row quad*4+r (at lane l16=row)
      float inv = 1.0f / lsum;
      int row = q0 + wave * 32 + i * 16 + quad * 4 + r;
#pragma unroll
      for (int oj = 0; oj < 4; ++oj)
        O[((size_t)(b * 2048 + row)) * 1024 + h * 64 + oj * 16 + l16] =
            (bf16)(o[i][oj][r] * inv);
    }
}

// ---------------------------------------------------------------- launch
extern "C" void kernel_launch(void* const* d_in, const int* in_sizes, int n_in,
                              void* d_out, int out_size, void* d_ws, size_t ws_size,
                              hipStream_t stream) {
  const float* x      = (const float*)d_in[0];   // [2,2048,1024]
  const float* qkv_w  = (const float*)d_in[1];   // [3072,1024]
  const float* qkv_b  = (const float*)d_in[2];   // [3072]
  const float* out_w  = (const float*)d_in[3];   // [1024,1024]
  const float* out_b  = (const float*)d_in[4];   // [1024]
  float* out = (float*)d_out;                    // [2,2048,1024] fp32

  char* ws = (char*)d_ws;
  bf16* Xb   = (bf16*)(ws);                      // 8 MB
  bf16* Wqkv = (bf16*)(ws + 8388608);            // 6 MB
  bf16* Wout = (bf16*)(ws + 14680064);           // 2 MB
  bf16* QKV  = (bf16*)(ws + 16777216);           // 24 MB: [Q][K] + V^T third
  bf16* At   = (bf16*)(ws + 41943040);           // 8 MB attn output [B,S,1024]
  bf16* VtP  = QKV + (size_t)2 * 32 * 2048 * 64; // V^T [32][64][2048]

  f2bf_all<<<8192, 256, 0, stream>>>(x, Xb, qkv_w, Wqkv, out_w, Wout);

  gemm_bt<0, 128><<<dim3(32, 24), 256, 0, stream>>>(Xb, Wqkv, qkv_b, (void*)QKV, 1024, 3072);

  // grid (bh, q_tile): blk%8 = bh%8 -> per-head XCD locality (K/V stay in one L2)
  attn_kernel<<<dim3(32, 16), 256, 0, stream>>>(QKV, VtP, At);

  gemm_bt<1, 64><<<dim3(32, 16), 256, 0, stream>>>(At, Wout, out_b, (void*)out, 1024, 1024);
}